// Round 1
// baseline (156.530 us; speedup 1.0000x reference)
//
#include <hip/hip_runtime.h>
#include <cfloat>

#define SS 900      // sequence length (30*30)
#define WD 8
#define BD 8
#define NROWS 64    // B*W
#define OUT_ELEMS (BD * SS * WD)  // 57600

__global__ __launch_bounds__(256) void rel_zero(float* __restrict__ out) {
    int i = blockIdx.x * 256 + threadIdx.x;
    if (i < OUT_ELEMS) out[i] = 0.0f;
}

// One block per (n, t) row: computes argmax_s( softmax_s(q_t*k_s) + gumbel_noise )
// and scatter-adds radar[n,t] into out[b, 0, idx, w].
__global__ __launch_bounds__(256) void rel_main(
    const float* __restrict__ radar,   // [W,B,900] flat
    const float* __restrict__ mde,     // [W,B,900] flat
    const float* __restrict__ gumbel,  // [N,900,900] flat
    const float* __restrict__ pWq, const float* __restrict__ pbq,
    const float* __restrict__ pWk, const float* __restrict__ pbk,
    float* __restrict__ out)           // [B,900,W] flat, pre-zeroed
{
    const int row = blockIdx.x;        // n*SS + t
    const int n   = row / SS;
    const int t   = row - n * SS;
    const int b   = n >> 3;            // n = b*W + w
    const int w   = n & 7;
    const int tid = threadIdx.x;
    const int lane = tid & 63;
    const int wv   = tid >> 6;

    __shared__ float s_redA[4];
    __shared__ float s_redB[4];
    __shared__ float s_redV[4];
    __shared__ int   s_redI[4];

    const float* __restrict__ mrow = mde   + (size_t)(w * BD + b) * SS;
    const float* __restrict__ rrow = radar + (size_t)(w * BD + b) * SS;
    const float* __restrict__ grow = gumbel + (size_t)row * SS;

    const float wq  = pWq[0], bq0 = pbq[0];
    const float wk  = pWk[0], bk0 = pbk[0];
    const float q   = rrow[t] * wq + bq0;

    // ---- pass 1: logits l_s = q * (mde_s*Wk + bk); row max ----
    float lv[4];
    float lmax = -FLT_MAX;
    #pragma unroll
    for (int i = 0; i < 4; i++) {
        int s = tid + i * 256;
        if (s < SS) {
            float k = mrow[s] * wk + bk0;
            float l = q * k;
            lv[i] = l;
            lmax = fmaxf(lmax, l);
        } else {
            lv[i] = -FLT_MAX;
        }
    }
    #pragma unroll
    for (int off = 32; off; off >>= 1)
        lmax = fmaxf(lmax, __shfl_down(lmax, off, 64));
    if (lane == 0) s_redA[wv] = lmax;
    __syncthreads();
    const float m = fmaxf(fmaxf(s_redA[0], s_redA[1]), fmaxf(s_redA[2], s_redA[3]));

    // ---- pass 2: e_s = exp(l_s - m); denom ----
    float ev[4];
    float lsum = 0.0f;
    #pragma unroll
    for (int i = 0; i < 4; i++) {
        int s = tid + i * 256;
        if (s < SS) {
            float e = expf(lv[i] - m);
            ev[i] = e;
            lsum += e;
        } else {
            ev[i] = 0.0f;
        }
    }
    #pragma unroll
    for (int off = 32; off; off >>= 1)
        lsum += __shfl_down(lsum, off, 64);
    if (lane == 0) s_redB[wv] = lsum;
    __syncthreads();
    const float denom = (s_redB[0] + s_redB[1]) + (s_redB[2] + s_redB[3]);

    // ---- pass 3: val = attn + gumbel noise; argmax (first-index ties) ----
    float bestv = -FLT_MAX;
    int   besti = 0x7fffffff;
    #pragma unroll
    for (int i = 0; i < 4; i++) {
        int s = tid + i * 256;
        if (s < SS) {
            float u  = grow[s];
            float nz = -logf(-logf(u + 1e-8f) + 1e-8f);
            float val = ev[i] / denom + nz;
            if (val > bestv) { bestv = val; besti = s; }  // strict >: keeps lowest s
        }
    }
    #pragma unroll
    for (int off = 32; off; off >>= 1) {
        float ov = __shfl_down(bestv, off, 64);
        int   oi = __shfl_down(besti, off, 64);
        if (ov > bestv || (ov == bestv && oi < besti)) { bestv = ov; besti = oi; }
    }
    if (lane == 0) { s_redV[wv] = bestv; s_redI[wv] = besti; }
    __syncthreads();
    if (tid == 0) {
        float bv = s_redV[0]; int bi = s_redI[0];
        #pragma unroll
        for (int i = 1; i < 4; i++) {
            if (s_redV[i] > bv || (s_redV[i] == bv && s_redI[i] < bi)) {
                bv = s_redV[i]; bi = s_redI[i];
            }
        }
        // out[b, 0, bi, w]
        atomicAdd(&out[((size_t)b * SS + bi) * WD + w], rrow[t]);
    }
}

// out += valid * (out != 0) * (attn_residual_scale * ln_beta)
__global__ __launch_bounds__(256) void rel_epilogue(
    const float* __restrict__ radar,
    const float* __restrict__ pScale,
    const float* __restrict__ pBeta,
    float* __restrict__ out)
{
    int i = blockIdx.x * 256 + threadIdx.x;
    if (i >= OUT_ELEMS) return;
    int w    = i & 7;
    int rest = i >> 3;
    int s    = rest % SS;
    int b    = rest / SS;
    float o = out[i];
    float r = radar[(size_t)(w * BD + b) * SS + s];
    float add = ((r != 0.0f) && (o != 0.0f)) ? (pScale[0] * pBeta[0]) : 0.0f;
    out[i] = o + add;
}

extern "C" void kernel_launch(void* const* d_in, const int* in_sizes, int n_in,
                              void* d_out, int out_size, void* d_ws, size_t ws_size,
                              hipStream_t stream) {
    const float* radar  = (const float*)d_in[0];
    const float* mde    = (const float*)d_in[1];
    const float* gumbel = (const float*)d_in[2];
    const float* Wq     = (const float*)d_in[3];
    const float* bq     = (const float*)d_in[4];
    const float* Wk     = (const float*)d_in[5];
    const float* bk     = (const float*)d_in[6];
    // d_in[7..10] = Wv, bv, Wo, bo  (dead: LayerNorm over dim-1 kills the attended path)
    const float* beta   = (const float*)d_in[12];
    const float* scale  = (const float*)d_in[13];
    float* out = (float*)d_out;

    rel_zero<<<(OUT_ELEMS + 255) / 256, 256, 0, stream>>>(out);
    rel_main<<<NROWS * SS, 256, 0, stream>>>(radar, mde, gumbel, Wq, bq, Wk, bk, out);
    rel_epilogue<<<(OUT_ELEMS + 255) / 256, 256, 0, stream>>>(radar, scale, beta, out);
}

// Round 2
// 53.599 us; speedup vs baseline: 2.9204x; 2.9204x over previous
//
#include <hip/hip_runtime.h>
#include <cfloat>

#define SS 900      // sequence length (30*30)
#define WD 8
#define BD 8
#define NROWS 64    // B*W
#define OUT_ELEMS (BD * SS * WD)  // 57600
#define NQ 225      // float4s per row (900/4)

__global__ __launch_bounds__(256) void rel_zero(float* __restrict__ out) {
    int i = blockIdx.x * 256 + threadIdx.x;
    if (i < OUT_ELEMS) out[i] = 0.0f;
}

// One WAVE per (n,t) row. argmax_s( p_s + nz_s ) with p = softmax(q*k),
// nz = -log(-log(u+1e-8)+1e-8). nz is monotone increasing in u, and p<=1,
// so winner has nz_s >= nz(u_max)-1  =>  u_s >= u_thr (computed by inverting
// nz once per row). Only ~3 candidates/row need the precise logf/expf/div.
// D (softmax denom) uses hw __expf: relative error ~1e-7, safe for argmax.
__global__ __launch_bounds__(256) void rel_main(
    const float* __restrict__ radar,   // [W,B,900]
    const float* __restrict__ mde,     // [W,B,900]
    const float* __restrict__ gumbel,  // [N,900,900]
    const float* __restrict__ pWq, const float* __restrict__ pbq,
    const float* __restrict__ pWk, const float* __restrict__ pbk,
    float* __restrict__ out)           // [B,900,W], pre-zeroed
{
    const int wid  = threadIdx.x >> 6;
    const int lane = threadIdx.x & 63;
    const int row  = blockIdx.x * 4 + wid;   // grid is exact: 57600/4 blocks
    const int n    = row / SS;
    const int t    = row - n * SS;
    const int b    = n >> 3;                 // n = b*W + w
    const int w    = n & 7;

    const float wq = pWq[0], bq0 = pbq[0];
    const float wk = pWk[0], bk0 = pbk[0];

    const float4* __restrict__ g4   = (const float4*)(gumbel + (size_t)row * SS);
    const float4* __restrict__ m4   = (const float4*)(mde + (size_t)(w * BD + b) * SS);
    const float*  __restrict__ rrow = radar + (size_t)(w * BD + b) * SS;

    // ---- pass A: load u (keep in regs) + k (keep in regs); track umax, kmin, kmax ----
    float4 U[4], K[4];
    float umax = -1.0f, kmin = FLT_MAX, kmax = -FLT_MAX;
    #pragma unroll
    for (int j = 0; j < 4; j++) {
        int f = j * 64 + lane;
        bool valid = (f < NQ);
        int fc = valid ? f : 0;
        float4 u  = g4[fc];
        float4 mq = m4[fc];
        float4 k;
        k.x = __fmaf_rn(mq.x, wk, bk0);
        k.y = __fmaf_rn(mq.y, wk, bk0);
        k.z = __fmaf_rn(mq.z, wk, bk0);
        k.w = __fmaf_rn(mq.w, wk, bk0);
        K[j] = k;
        if (!valid) { u.x = u.y = u.z = u.w = -1.0f; }  // never passes filter
        U[j] = u;
        umax = fmaxf(umax, fmaxf(fmaxf(u.x, u.y), fmaxf(u.z, u.w)));
        kmin = fminf(kmin, fminf(fminf(k.x, k.y), fminf(k.z, k.w)));
        kmax = fmaxf(kmax, fmaxf(fmaxf(k.x, k.y), fmaxf(k.z, k.w)));
    }
    #pragma unroll
    for (int off = 1; off < 64; off <<= 1) {
        umax = fmaxf(umax, __shfl_xor(umax, off, 64));
        kmin = fminf(kmin, __shfl_xor(kmin, off, 64));
        kmax = fmaxf(kmax, __shfl_xor(kmax, off, 64));
    }

    const float q = __fmaf_rn(rrow[t], wq, bq0);
    // max_s fl(q*k_s) == fl(q * k_ext) by monotonicity of rounding
    const float m = __fmul_rn(q, (q >= 0.0f) ? kmax : kmin);

    // ---- invert nz to a u-threshold (margin 0.05 + downward fudges: inclusive) ----
    // nz(u) >= T  <=>  u >= exp(-(exp(-T) - 1e-8)) - 1e-8
    float w0    = -logf(umax + 1e-8f);
    float nzmax = -logf(w0 + 1e-8f);
    float T     = nzmax - 1.05f;
    float wT    = expf(-T);
    float uthr  = expf(-(wT - 1e-8f)) - 1e-8f;
    uthr = uthr - fabsf(uthr) * 4e-6f - 1e-9f;

    // ---- pass B: D = sum_s exp(l_s - m) with hardware exp ----
    float D = 0.0f;
    #pragma unroll
    for (int j = 0; j < 4; j++) {
        int f = j * 64 + lane;
        if (f < NQ) {
            float4 k = K[j];
            float l0 = __fmul_rn(q, k.x);
            float l1 = __fmul_rn(q, k.y);
            float l2 = __fmul_rn(q, k.z);
            float l3 = __fmul_rn(q, k.w);
            D += __expf(l0 - m) + __expf(l1 - m) + __expf(l2 - m) + __expf(l3 - m);
        }
    }
    #pragma unroll
    for (int off = 1; off < 64; off <<= 1)
        D += __shfl_xor(D, off, 64);

    // ---- pass C: filter by u_thr; precise eval only for candidates ----
    float bestv = -FLT_MAX;
    int   besti = 0x7fffffff;
    #pragma unroll
    for (int j = 0; j < 4; j++) {
        int f = j * 64 + lane;
        float4 u = U[j];
        float4 k = K[j];
        int s0 = f * 4;
        if (u.x >= uthr) {
            float l = __fmul_rn(q, k.x);
            float nz = -logf(-logf(u.x + 1e-8f) + 1e-8f);
            float v = expf(l - m) / D + nz;
            if (v > bestv) { bestv = v; besti = s0; }
        }
        if (u.y >= uthr) {
            float l = __fmul_rn(q, k.y);
            float nz = -logf(-logf(u.y + 1e-8f) + 1e-8f);
            float v = expf(l - m) / D + nz;
            if (v > bestv) { bestv = v; besti = s0 + 1; }
        }
        if (u.z >= uthr) {
            float l = __fmul_rn(q, k.z);
            float nz = -logf(-logf(u.z + 1e-8f) + 1e-8f);
            float v = expf(l - m) / D + nz;
            if (v > bestv) { bestv = v; besti = s0 + 2; }
        }
        if (u.w >= uthr) {
            float l = __fmul_rn(q, k.w);
            float nz = -logf(-logf(u.w + 1e-8f) + 1e-8f);
            float v = expf(l - m) / D + nz;
            if (v > bestv) { bestv = v; besti = s0 + 3; }
        }
    }
    #pragma unroll
    for (int off = 1; off < 64; off <<= 1) {
        float ov = __shfl_xor(bestv, off, 64);
        int   oi = __shfl_xor(besti, off, 64);
        if (ov > bestv || (ov == bestv && oi < besti)) { bestv = ov; besti = oi; }
    }
    if (lane == 0)
        atomicAdd(&out[((size_t)b * SS + besti) * WD + w], rrow[t]);
}

// out += valid * (out != 0) * (attn_residual_scale * ln_beta)
__global__ __launch_bounds__(256) void rel_epilogue(
    const float* __restrict__ radar,
    const float* __restrict__ pScale,
    const float* __restrict__ pBeta,
    float* __restrict__ out)
{
    int i = blockIdx.x * 256 + threadIdx.x;
    if (i >= OUT_ELEMS) return;
    int w    = i & 7;
    int rest = i >> 3;
    int s    = rest % SS;
    int b    = rest / SS;
    float o = out[i];
    float r = radar[(size_t)(w * BD + b) * SS + s];
    float add = ((r != 0.0f) && (o != 0.0f)) ? (pScale[0] * pBeta[0]) : 0.0f;
    out[i] = o + add;
}

extern "C" void kernel_launch(void* const* d_in, const int* in_sizes, int n_in,
                              void* d_out, int out_size, void* d_ws, size_t ws_size,
                              hipStream_t stream) {
    const float* radar  = (const float*)d_in[0];
    const float* mde    = (const float*)d_in[1];
    const float* gumbel = (const float*)d_in[2];
    const float* Wq     = (const float*)d_in[3];
    const float* bq     = (const float*)d_in[4];
    const float* Wk     = (const float*)d_in[5];
    const float* bk     = (const float*)d_in[6];
    // d_in[7..11] = Wv, bv, Wo, bo, ln_gamma (dead: LN over dim-1 => attended_out == ln_beta)
    const float* beta   = (const float*)d_in[12];
    const float* scale  = (const float*)d_in[13];
    float* out = (float*)d_out;

    rel_zero<<<(OUT_ELEMS + 255) / 256, 256, 0, stream>>>(out);
    rel_main<<<(NROWS * SS) / 4, 256, 0, stream>>>(radar, mde, gumbel, Wq, bq, Wk, bk, out);
    rel_epilogue<<<(OUT_ELEMS + 255) / 256, 256, 0, stream>>>(radar, scale, beta, out);
}

// Round 3
// 51.154 us; speedup vs baseline: 3.0599x; 1.0478x over previous
//
#include <hip/hip_runtime.h>
#include <cfloat>

#define SS 900      // sequence length (30*30)
#define WD 8
#define BD 8
#define NROWS 64    // B*W
#define OUT_ELEMS (BD * SS * WD)  // 57600
#define NQ 225      // float4s per row (900/4)
#define KPAD 904    // padded k-row stride (float4-aligned)

// Per-n precompute: k[n][s] = fl(mde*Wk + bk), kmin/kmax per n; also zero out.
__global__ __launch_bounds__(256) void rel_prep(
    const float* __restrict__ mde,     // [W,B,900]
    const float* __restrict__ pWk, const float* __restrict__ pbk,
    float* __restrict__ kws,           // [64][KPAD]
    float* __restrict__ kext,          // [64][2] = {kmin, kmax}
    float* __restrict__ out)           // [B,900,W] -> zeroed
{
    const int tid = threadIdx.x;
    const int n   = blockIdx.x;        // 64 blocks

    // zero the output (grid-strided across the 64 blocks)
    for (int i = n * 256 + tid; i < OUT_ELEMS; i += 64 * 256) out[i] = 0.0f;

    const float wk = pWk[0], bk0 = pbk[0];
    const int b = n >> 3, w = n & 7;
    const float* __restrict__ mrow = mde + (size_t)(w * BD + b) * SS;

    float kmin = FLT_MAX, kmax = -FLT_MAX;
    #pragma unroll
    for (int j = 0; j < 4; j++) {
        int s = j * 256 + tid;
        if (s < SS) {
            float k = __fmaf_rn(mrow[s], wk, bk0);
            kws[(size_t)n * KPAD + s] = k;
            kmin = fminf(kmin, k);
            kmax = fmaxf(kmax, k);
        }
    }
    #pragma unroll
    for (int off = 1; off < 64; off <<= 1) {
        kmin = fminf(kmin, __shfl_xor(kmin, off, 64));
        kmax = fmaxf(kmax, __shfl_xor(kmax, off, 64));
    }
    __shared__ float s_min[4], s_max[4];
    if ((tid & 63) == 0) { s_min[tid >> 6] = kmin; s_max[tid >> 6] = kmax; }
    __syncthreads();
    if (tid == 0) {
        kext[2 * n]     = fminf(fminf(s_min[0], s_min[1]), fminf(s_min[2], s_min[3]));
        kext[2 * n + 1] = fmaxf(fmaxf(s_max[0], s_max[1]), fmaxf(s_max[2], s_max[3]));
    }
}

// One WAVE per (n,t) row; 4 waves/block all share the same n (900 % 4 == 0).
// Single fused pass: load u + k, accumulate D = sum exp(q*k - m), track umax.
// Then invert the monotone gumbel transform to a u-threshold; only candidates
// get the precise libm logf/expf/div evaluation (matches reference exactly).
__global__ __launch_bounds__(256) void rel_main(
    const float* __restrict__ radar,   // [W,B,900]
    const float* __restrict__ gumbel,  // [N,900,900]
    const float* __restrict__ kws,     // [64][KPAD]
    const float* __restrict__ kext,    // [64][2]
    const float* __restrict__ pWq, const float* __restrict__ pbq,
    float* __restrict__ out)           // [B,900,W], pre-zeroed
{
    const int wid  = threadIdx.x >> 6;
    const int lane = threadIdx.x & 63;
    const int row  = blockIdx.x * 4 + wid;   // 57600/4 blocks, exact
    const int n    = row / SS;
    const int t    = row - n * SS;
    const int b    = n >> 3;                 // n = b*W + w
    const int w    = n & 7;

    const float4* __restrict__ g4 = (const float4*)(gumbel + (size_t)row * SS);
    const float4* __restrict__ k4 = (const float4*)(kws + (size_t)n * KPAD);
    const float*  __restrict__ rrow = radar + (size_t)(w * BD + b) * SS;

    const float q = __fmaf_rn(rrow[t], pWq[0], pbq[0]);
    const float kmin = kext[2 * n], kmax = kext[2 * n + 1];
    // max_s fl(q*k_s) == fl(q*k_ext) by monotonicity of rounding
    const float m = __fmul_rn(q, (q >= 0.0f) ? kmax : kmin);

    // ---- fused pass: umax + D; keep u,k in regs ----
    float4 U[4], K[4];
    float umax = -1.0f;
    float D = 0.0f;
    #pragma unroll
    for (int j = 0; j < 4; j++) {
        int f = j * 64 + lane;
        bool valid = (f < NQ);
        int fc = valid ? f : 0;
        float4 u = g4[fc];
        float4 k = k4[fc];
        K[j] = k;
        if (!valid) { u.x = u.y = u.z = u.w = -1.0f; }  // never passes filter
        U[j] = u;
        umax = fmaxf(umax, fmaxf(fmaxf(u.x, u.y), fmaxf(u.z, u.w)));
        if (valid) {
            D += __expf(__fmaf_rn(q, k.x, -m)) + __expf(__fmaf_rn(q, k.y, -m))
               + __expf(__fmaf_rn(q, k.z, -m)) + __expf(__fmaf_rn(q, k.w, -m));
        }
    }
    #pragma unroll
    for (int off = 1; off < 64; off <<= 1) {
        umax = fmaxf(umax, __shfl_xor(umax, off, 64));
        D += __shfl_xor(D, off, 64);
    }

    // ---- invert nz to a u-threshold (margin 0.05 + downward fudges) ----
    // nz(u) >= T  <=>  u >= exp(-(exp(-T) - 1e-8)) - 1e-8
    float w0    = -logf(umax + 1e-8f);
    float nzmax = -logf(w0 + 1e-8f);
    float T     = nzmax - 1.05f;
    float wT    = expf(-T);
    float uthr  = expf(-(wT - 1e-8f)) - 1e-8f;
    uthr = uthr - fabsf(uthr) * 4e-6f - 1e-9f;

    // ---- candidate pass: precise eval only where u >= uthr ----
    float bestv = -FLT_MAX;
    int   besti = 0x7fffffff;
    #pragma unroll
    for (int j = 0; j < 4; j++) {
        int f = j * 64 + lane;
        float4 u = U[j];
        float4 k = K[j];
        int s0 = f * 4;
        if (u.x >= uthr) {
            float l = __fmul_rn(q, k.x);
            float nz = -logf(-logf(u.x + 1e-8f) + 1e-8f);
            float v = expf(l - m) / D + nz;
            if (v > bestv) { bestv = v; besti = s0; }
        }
        if (u.y >= uthr) {
            float l = __fmul_rn(q, k.y);
            float nz = -logf(-logf(u.y + 1e-8f) + 1e-8f);
            float v = expf(l - m) / D + nz;
            if (v > bestv) { bestv = v; besti = s0 + 1; }
        }
        if (u.z >= uthr) {
            float l = __fmul_rn(q, k.z);
            float nz = -logf(-logf(u.z + 1e-8f) + 1e-8f);
            float v = expf(l - m) / D + nz;
            if (v > bestv) { bestv = v; besti = s0 + 2; }
        }
        if (u.w >= uthr) {
            float l = __fmul_rn(q, k.w);
            float nz = -logf(-logf(u.w + 1e-8f) + 1e-8f);
            float v = expf(l - m) / D + nz;
            if (v > bestv) { bestv = v; besti = s0 + 3; }
        }
    }
    #pragma unroll
    for (int off = 1; off < 64; off <<= 1) {
        float ov = __shfl_xor(bestv, off, 64);
        int   oi = __shfl_xor(besti, off, 64);
        if (ov > bestv || (ov == bestv && oi < besti)) { bestv = ov; besti = oi; }
    }
    if (lane == 0)
        atomicAdd(&out[((size_t)b * SS + besti) * WD + w], rrow[t]);
}

// out += valid * (out != 0) * (attn_residual_scale * ln_beta)
__global__ __launch_bounds__(256) void rel_epilogue(
    const float* __restrict__ radar,
    const float* __restrict__ pScale,
    const float* __restrict__ pBeta,
    float* __restrict__ out)
{
    int i = blockIdx.x * 256 + threadIdx.x;
    if (i >= OUT_ELEMS) return;
    int w    = i & 7;
    int rest = i >> 3;
    int s    = rest % SS;
    int b    = rest / SS;
    float o = out[i];
    float r = radar[(size_t)(w * BD + b) * SS + s];
    float add = ((r != 0.0f) && (o != 0.0f)) ? (pScale[0] * pBeta[0]) : 0.0f;
    out[i] = o + add;
}

extern "C" void kernel_launch(void* const* d_in, const int* in_sizes, int n_in,
                              void* d_out, int out_size, void* d_ws, size_t ws_size,
                              hipStream_t stream) {
    const float* radar  = (const float*)d_in[0];
    const float* mde    = (const float*)d_in[1];
    const float* gumbel = (const float*)d_in[2];
    const float* Wq     = (const float*)d_in[3];
    const float* bq     = (const float*)d_in[4];
    const float* Wk     = (const float*)d_in[5];
    const float* bk     = (const float*)d_in[6];
    // d_in[7..11] = Wv, bv, Wo, bo, ln_gamma (dead: LN over dim-1 => attended_out == ln_beta)
    const float* beta   = (const float*)d_in[12];
    const float* scale  = (const float*)d_in[13];
    float* out = (float*)d_out;

    float* kws  = (float*)d_ws;                       // [64][KPAD]
    float* kext = kws + (size_t)NROWS * KPAD;         // [64][2]

    rel_prep<<<NROWS, 256, 0, stream>>>(mde, Wk, bk, kws, kext, out);
    rel_main<<<(NROWS * SS) / 4, 256, 0, stream>>>(radar, gumbel, kws, kext, Wq, bq, out);
    rel_epilogue<<<(OUT_ELEMS + 255) / 256, 256, 0, stream>>>(radar, scale, beta, out);
}

// Round 4
// 46.431 us; speedup vs baseline: 3.3713x; 1.1017x over previous
//
#include <hip/hip_runtime.h>
#include <cfloat>

#define SS 900      // sequence length (30*30)
#define WD 8
#define BD 8
#define NROWS 64    // B*W
#define OUT_ELEMS (BD * SS * WD)  // 57600
#define NQ 225      // float4s per row (900/4)
#define KPAD 904    // padded k-row stride (float4-aligned)

// Per-n precompute: k[n][s] = fl(mde*Wk + bk), kmin/kmax per n; also zero out.
__global__ __launch_bounds__(256) void rel_prep(
    const float* __restrict__ mde,     // [W,B,900]
    const float* __restrict__ pWk, const float* __restrict__ pbk,
    float* __restrict__ kws,           // [64][KPAD]
    float* __restrict__ kext,          // [64][2] = {kmin, kmax}
    float* __restrict__ out)           // [B,900,W] -> zeroed
{
    const int tid = threadIdx.x;
    const int n   = blockIdx.x;        // 64 blocks

    for (int i = n * 256 + tid; i < OUT_ELEMS; i += 64 * 256) out[i] = 0.0f;

    const float wk = pWk[0], bk0 = pbk[0];
    const int b = n >> 3, w = n & 7;
    const float* __restrict__ mrow = mde + (size_t)(w * BD + b) * SS;

    float kmin = FLT_MAX, kmax = -FLT_MAX;
    #pragma unroll
    for (int j = 0; j < 4; j++) {
        int s = j * 256 + tid;
        if (s < SS) {
            float k = __fmaf_rn(mrow[s], wk, bk0);
            kws[(size_t)n * KPAD + s] = k;
            kmin = fminf(kmin, k);
            kmax = fmaxf(kmax, k);
        }
    }
    #pragma unroll
    for (int off = 1; off < 64; off <<= 1) {
        kmin = fminf(kmin, __shfl_xor(kmin, off, 64));
        kmax = fmaxf(kmax, __shfl_xor(kmax, off, 64));
    }
    __shared__ float s_min[4], s_max[4];
    if ((tid & 63) == 0) { s_min[tid >> 6] = kmin; s_max[tid >> 6] = kmax; }
    __syncthreads();
    if (tid == 0) {
        kext[2 * n]     = fminf(fminf(s_min[0], s_min[1]), fminf(s_min[2], s_min[3]));
        kext[2 * n + 1] = fmaxf(fmaxf(s_max[0], s_max[1]), fmaxf(s_max[2], s_max[3]));
    }
}

// 16 lanes per (n,t) row; 4 rows per wave; 4 waves per block -> 16 rows/block.
// Fused pass: umax + D = sum exp(q*k - m) with k precomputed, m known upfront.
// Winner must have nz >= nzmax - p_win, and p_s <= 1/D exactly (l - m <= 0),
// so margin = 1.002/D + 1e-6 -> ~1.1 candidates/row get the precise libm path.
__global__ __launch_bounds__(256) void rel_main(
    const float* __restrict__ radar,   // [W,B,900]
    const float* __restrict__ gumbel,  // [N,900,900]
    const float* __restrict__ kws,     // [64][KPAD]
    const float* __restrict__ kext,    // [64][2]
    const float* __restrict__ pWq, const float* __restrict__ pbq,
    float* __restrict__ out)           // [B,900,W], pre-zeroed
{
    const int tid    = threadIdx.x;
    const int wid    = tid >> 6;
    const int g      = (tid >> 4) & 3;     // 16-lane group within wave
    const int lane16 = tid & 15;
    const int row    = blockIdx.x * 16 + wid * 4 + g;   // 3600 blocks, exact
    const int n      = row / SS;
    const int t      = row - n * SS;
    const int b      = n >> 3;             // n = b*W + w
    const int w      = n & 7;

    const float4* __restrict__ g4 = (const float4*)(gumbel + (size_t)row * SS);
    const float4* __restrict__ k4 = (const float4*)(kws + (size_t)n * KPAD);
    const float*  __restrict__ krow = kws + (size_t)n * KPAD;

    const float r0 = radar[(size_t)(w * BD + b) * SS + t];
    const float q  = __fmaf_rn(r0, pWq[0], pbq[0]);
    const float kmin = kext[2 * n], kmax = kext[2 * n + 1];
    // max_s fl(q*k_s) == fl(q*k_ext) by monotonicity of rounding
    const float m = __fmul_rn(q, (q >= 0.0f) ? kmax : kmin);

    // ---- fused stream: umax + D; keep u in regs (15 float4/lane) ----
    float4 U[15];
    float umax = -1.0f;
    float D = 0.0f;
    #pragma unroll
    for (int j = 0; j < 15; j++) {
        const int f = j * 16 + lane16;
        const bool valid = (j < 14) || (lane16 == 0);   // 225 = 14*16 + 1
        const int fc = valid ? f : 0;
        float4 u = g4[fc];
        float4 k = k4[fc];
        if (!valid) { u.x = u.y = u.z = u.w = -1.0f; }
        U[j] = u;
        umax = fmaxf(umax, fmaxf(fmaxf(u.x, u.y), fmaxf(u.z, u.w)));
        if (valid) {
            D += __expf(__fmaf_rn(q, k.x, -m)) + __expf(__fmaf_rn(q, k.y, -m))
               + __expf(__fmaf_rn(q, k.z, -m)) + __expf(__fmaf_rn(q, k.w, -m));
        }
    }
    #pragma unroll
    for (int off = 1; off < 16; off <<= 1) {
        umax = fmaxf(umax, __shfl_xor(umax, off, 16));
        D += __shfl_xor(D, off, 16);
    }

    // ---- u-threshold: winner has nz >= nzmax - margin, margin ~ 1/D ----
    // nz(u) >= T  <=>  u >= exp(-(exp(-T) - 1e-8)) - 1e-8   (monotone)
    float margin = __fmaf_rn(1.002f, 1.0f / D, 1e-6f);
    float w0    = -logf(umax + 1e-8f);
    float nzmax = -logf(w0 + 1e-8f);
    float T     = nzmax - margin;
    float wT    = expf(-T);
    float uthr  = expf(-(wT - 1e-8f)) - 1e-8f;
    uthr = uthr - fabsf(uthr) * 4e-6f - 1e-9f;   // downward: inclusive filter

    // ---- candidate pass: precise libm eval only where u >= uthr ----
    float bestv = -FLT_MAX;
    int   besti = 0x7fffffff;
    #pragma unroll
    for (int j = 0; j < 15; j++) {
        float4 u = U[j];
        float m4 = fmaxf(fmaxf(u.x, u.y), fmaxf(u.z, u.w));
        if (__any(m4 >= uthr)) {
            const int s0 = (j * 16 + lane16) * 4;
            if (u.x >= uthr) {
                float l = __fmul_rn(q, krow[s0]);
                float nz = -logf(-logf(u.x + 1e-8f) + 1e-8f);
                float v = expf(l - m) / D + nz;
                if (v > bestv) { bestv = v; besti = s0; }
            }
            if (u.y >= uthr) {
                float l = __fmul_rn(q, krow[s0 + 1]);
                float nz = -logf(-logf(u.y + 1e-8f) + 1e-8f);
                float v = expf(l - m) / D + nz;
                if (v > bestv) { bestv = v; besti = s0 + 1; }
            }
            if (u.z >= uthr) {
                float l = __fmul_rn(q, krow[s0 + 2]);
                float nz = -logf(-logf(u.z + 1e-8f) + 1e-8f);
                float v = expf(l - m) / D + nz;
                if (v > bestv) { bestv = v; besti = s0 + 2; }
            }
            if (u.w >= uthr) {
                float l = __fmul_rn(q, krow[s0 + 3]);
                float nz = -logf(-logf(u.w + 1e-8f) + 1e-8f);
                float v = expf(l - m) / D + nz;
                if (v > bestv) { bestv = v; besti = s0 + 3; }
            }
        }
    }
    #pragma unroll
    for (int off = 1; off < 16; off <<= 1) {
        float ov = __shfl_xor(bestv, off, 16);
        int   oi = __shfl_xor(besti, off, 16);
        if (ov > bestv || (ov == bestv && oi < besti)) { bestv = ov; besti = oi; }
    }
    if (lane16 == 0)
        atomicAdd(&out[((size_t)b * SS + besti) * WD + w], r0);
}

// out += valid * (out != 0) * (attn_residual_scale * ln_beta)
__global__ __launch_bounds__(256) void rel_epilogue(
    const float* __restrict__ radar,
    const float* __restrict__ pScale,
    const float* __restrict__ pBeta,
    float* __restrict__ out)
{
    int i = blockIdx.x * 256 + threadIdx.x;
    if (i >= OUT_ELEMS) return;
    int w    = i & 7;
    int rest = i >> 3;
    int s    = rest % SS;
    int b    = rest / SS;
    float o = out[i];
    float r = radar[(size_t)(w * BD + b) * SS + s];
    float add = ((r != 0.0f) && (o != 0.0f)) ? (pScale[0] * pBeta[0]) : 0.0f;
    out[i] = o + add;
}

extern "C" void kernel_launch(void* const* d_in, const int* in_sizes, int n_in,
                              void* d_out, int out_size, void* d_ws, size_t ws_size,
                              hipStream_t stream) {
    const float* radar  = (const float*)d_in[0];
    const float* mde    = (const float*)d_in[1];
    const float* gumbel = (const float*)d_in[2];
    const float* Wq     = (const float*)d_in[3];
    const float* bq     = (const float*)d_in[4];
    const float* Wk     = (const float*)d_in[5];
    const float* bk     = (const float*)d_in[6];
    // d_in[7..11] = Wv, bv, Wo, bo, ln_gamma (dead: LN over dim-1 => attended_out == ln_beta)
    const float* beta   = (const float*)d_in[12];
    const float* scale  = (const float*)d_in[13];
    float* out = (float*)d_out;

    float* kws  = (float*)d_ws;                       // [64][KPAD]
    float* kext = kws + (size_t)NROWS * KPAD;         // [64][2]

    rel_prep<<<NROWS, 256, 0, stream>>>(mde, Wk, bk, kws, kext, out);
    rel_main<<<(NROWS * SS) / 16, 256, 0, stream>>>(radar, gumbel, kws, kext, Wq, bq, out);
    rel_epilogue<<<(OUT_ELEMS + 255) / 256, 256, 0, stream>>>(radar, scale, beta, out);
}

// Round 5
// 45.041 us; speedup vs baseline: 3.4753x; 1.0309x over previous
//
#include <hip/hip_runtime.h>
#include <cfloat>

#define SS 900      // sequence length (30*30)
#define WD 8
#define BD 8
#define NROWS 64    // B*W
#define OUT_ELEMS (BD * SS * WD)  // 57600
#define NQ 225      // float4s per row (900/4)
#define ROWS_PER_BLK 16
#define BLKS_PER_N 57             // ceil(900/16)

__global__ __launch_bounds__(256) void rel_zero(float* __restrict__ out) {
    int i = blockIdx.x * 256 + threadIdx.x;
    if (i < OUT_ELEMS) out[i] = 0.0f;
}

// One block = 16 rows (16 lanes each) of a single n. k-row staged in LDS once.
// Per row: fused stream computes umax + D = sum __expf(q*k - m); monotone
// inversion of the gumbel transform gives a u-threshold; only ~1.1
// candidates/row take the precise libm logf/expf/div path (matches reference).
__global__ __launch_bounds__(256) void rel_main(
    const float* __restrict__ radar,   // [W,B,900]
    const float* __restrict__ mde,     // [W,B,900]
    const float* __restrict__ gumbel,  // [N,900,900]
    const float* __restrict__ pWq, const float* __restrict__ pbq,
    const float* __restrict__ pWk, const float* __restrict__ pbk,
    float* __restrict__ out)           // [B,900,W], pre-zeroed
{
    const int tid   = threadIdx.x;
    const int n     = blockIdx.x / BLKS_PER_N;
    const int tbase = (blockIdx.x - n * BLKS_PER_N) * ROWS_PER_BLK;
    const int b     = n >> 3;          // n = b*W + w
    const int w     = n & 7;

    __shared__ float4 ks4[NQ + 1];
    __shared__ float  s_red[8];

    // ---- stage k = fl(mde*Wk + bk) into LDS; exact block min/max ----
    const float wk = pWk[0], bk0 = pbk[0];
    float kmin = FLT_MAX, kmax = -FLT_MAX;
    if (tid < NQ) {
        const float4* __restrict__ m4 = (const float4*)(mde + (size_t)(w * BD + b) * SS);
        float4 mq = m4[tid];
        float4 k;
        k.x = __fmaf_rn(mq.x, wk, bk0);
        k.y = __fmaf_rn(mq.y, wk, bk0);
        k.z = __fmaf_rn(mq.z, wk, bk0);
        k.w = __fmaf_rn(mq.w, wk, bk0);
        ks4[tid] = k;
        kmin = fminf(fminf(k.x, k.y), fminf(k.z, k.w));
        kmax = fmaxf(fmaxf(k.x, k.y), fmaxf(k.z, k.w));
    }
    #pragma unroll
    for (int off = 1; off < 64; off <<= 1) {
        kmin = fminf(kmin, __shfl_xor(kmin, off, 64));
        kmax = fmaxf(kmax, __shfl_xor(kmax, off, 64));
    }
    if ((tid & 63) == 0) { s_red[tid >> 6] = kmin; s_red[4 + (tid >> 6)] = kmax; }
    __syncthreads();
    kmin = fminf(fminf(s_red[0], s_red[1]), fminf(s_red[2], s_red[3]));
    kmax = fmaxf(fmaxf(s_red[4], s_red[5]), fmaxf(s_red[6], s_red[7]));

    const int gg     = tid >> 4;
    const int lane16 = tid & 15;
    const int t      = tbase + gg;
    if (t >= SS) return;               // ragged tail (after barrier)
    const int row = n * SS + t;

    const float r0 = radar[(size_t)(w * BD + b) * SS + t];
    const float q  = __fmaf_rn(r0, pWq[0], pbq[0]);
    // max_s fl(q*k_s) == fl(q*k_ext) by monotonicity of rounding
    const float m  = __fmul_rn(q, (q >= 0.0f) ? kmax : kmin);

    const float4* __restrict__ g4 = (const float4*)(gumbel + (size_t)row * SS);
    const float*  __restrict__ kf = (const float*)ks4;

    // ---- fused stream: umax + D; u kept in regs (15 float4/lane) ----
    float4 U[15];
    float umax = -1.0f;
    float D = 0.0f;
    #pragma unroll
    for (int j = 0; j < 15; j++) {
        const int f = j * 16 + lane16;
        const bool valid = (j < 14) || (lane16 == 0);   // 225 = 14*16 + 1
        const int fc = valid ? f : 0;
        float4 u = g4[fc];
        float4 k = ks4[fc];
        if (!valid) { u.x = u.y = u.z = u.w = -1.0f; }
        U[j] = u;
        umax = fmaxf(umax, fmaxf(fmaxf(u.x, u.y), fmaxf(u.z, u.w)));
        if (valid) {
            D += __expf(__fmaf_rn(q, k.x, -m)) + __expf(__fmaf_rn(q, k.y, -m))
               + __expf(__fmaf_rn(q, k.z, -m)) + __expf(__fmaf_rn(q, k.w, -m));
        }
    }
    #pragma unroll
    for (int off = 1; off < 16; off <<= 1) {
        umax = fmaxf(umax, __shfl_xor(umax, off, 16));
        D += __shfl_xor(D, off, 16);
    }

    // ---- u-threshold: winner has nz >= nzmax - margin, margin ~ 1/D ----
    // nz(u) >= T  <=>  u >= exp(-(exp(-T) - 1e-8)) - 1e-8   (monotone)
    float margin = __fmaf_rn(1.002f, 1.0f / D, 1e-6f);
    float w0    = -logf(umax + 1e-8f);
    float nzmax = -logf(w0 + 1e-8f);
    float T     = nzmax - margin;
    float wT    = expf(-T);
    float uthr  = expf(-(wT - 1e-8f)) - 1e-8f;
    uthr = uthr - fabsf(uthr) * 4e-6f - 1e-9f;   // downward: inclusive filter

    // ---- candidate pass: precise libm eval only where u >= uthr ----
    float bestv = -FLT_MAX;
    int   besti = 0x7fffffff;
    #pragma unroll
    for (int j = 0; j < 15; j++) {
        float4 u = U[j];
        float m4 = fmaxf(fmaxf(u.x, u.y), fmaxf(u.z, u.w));
        if (__any(m4 >= uthr)) {
            const int s0 = (j * 16 + lane16) * 4;
            if (u.x >= uthr) {
                float l = __fmul_rn(q, kf[s0]);
                float nz = -logf(-logf(u.x + 1e-8f) + 1e-8f);
                float v = expf(l - m) / D + nz;
                if (v > bestv) { bestv = v; besti = s0; }
            }
            if (u.y >= uthr) {
                float l = __fmul_rn(q, kf[s0 + 1]);
                float nz = -logf(-logf(u.y + 1e-8f) + 1e-8f);
                float v = expf(l - m) / D + nz;
                if (v > bestv) { bestv = v; besti = s0 + 1; }
            }
            if (u.z >= uthr) {
                float l = __fmul_rn(q, kf[s0 + 2]);
                float nz = -logf(-logf(u.z + 1e-8f) + 1e-8f);
                float v = expf(l - m) / D + nz;
                if (v > bestv) { bestv = v; besti = s0 + 2; }
            }
            if (u.w >= uthr) {
                float l = __fmul_rn(q, kf[s0 + 3]);
                float nz = -logf(-logf(u.w + 1e-8f) + 1e-8f);
                float v = expf(l - m) / D + nz;
                if (v > bestv) { bestv = v; besti = s0 + 3; }
            }
        }
    }
    #pragma unroll
    for (int off = 1; off < 16; off <<= 1) {
        float ov = __shfl_xor(bestv, off, 16);
        int   oi = __shfl_xor(besti, off, 16);
        if (ov > bestv || (ov == bestv && oi < besti)) { bestv = ov; besti = oi; }
    }
    if (lane16 == 0)
        atomicAdd(&out[((size_t)b * SS + besti) * WD + w], r0);
}

// out += valid * (out != 0) * (attn_residual_scale * ln_beta)
__global__ __launch_bounds__(256) void rel_epilogue(
    const float* __restrict__ radar,
    const float* __restrict__ pScale,
    const float* __restrict__ pBeta,
    float* __restrict__ out)
{
    int i = blockIdx.x * 256 + threadIdx.x;
    if (i >= OUT_ELEMS) return;
    int w    = i & 7;
    int rest = i >> 3;
    int s    = rest % SS;
    int b    = rest / SS;
    float o = out[i];
    float r = radar[(size_t)(w * BD + b) * SS + s];
    float add = ((r != 0.0f) && (o != 0.0f)) ? (pScale[0] * pBeta[0]) : 0.0f;
    out[i] = o + add;
}

extern "C" void kernel_launch(void* const* d_in, const int* in_sizes, int n_in,
                              void* d_out, int out_size, void* d_ws, size_t ws_size,
                              hipStream_t stream) {
    const float* radar  = (const float*)d_in[0];
    const float* mde    = (const float*)d_in[1];
    const float* gumbel = (const float*)d_in[2];
    const float* Wq     = (const float*)d_in[3];
    const float* bq     = (const float*)d_in[4];
    const float* Wk     = (const float*)d_in[5];
    const float* bk     = (const float*)d_in[6];
    // d_in[7..11] = Wv, bv, Wo, bo, ln_gamma (dead: LN over dim-1 => attended_out == ln_beta)
    const float* beta   = (const float*)d_in[12];
    const float* scale  = (const float*)d_in[13];
    float* out = (float*)d_out;

    rel_zero<<<(OUT_ELEMS + 255) / 256, 256, 0, stream>>>(out);
    rel_main<<<NROWS * BLKS_PER_N, 256, 0, stream>>>(radar, mde, gumbel,
                                                     Wq, bq, Wk, bk, out);
    rel_epilogue<<<(OUT_ELEMS + 255) / 256, 256, 0, stream>>>(radar, scale, beta, out);
}

// Round 6
// 44.548 us; speedup vs baseline: 3.5137x; 1.0111x over previous
//
#include <hip/hip_runtime.h>
#include <cfloat>

#define SS 900      // sequence length (30*30)
#define WD 8
#define BD 8
#define NROWS 64    // B*W
#define OUT_ELEMS (BD * SS * WD)  // 57600
#define NQ 225      // float4s per row (900/4)
#define ROWS_PER_BLK 16
#define BLKS_PER_N 57             // ceil(900/16)
#define CAP 128                   // candidate queue capacity per block

__global__ __launch_bounds__(256) void rel_zero(float4* __restrict__ out4) {
    int i = blockIdx.x * 256 + threadIdx.x;
    if (i < OUT_ELEMS / 4) out4[i] = make_float4(0.f, 0.f, 0.f, 0.f);
}

// One block = 16 rows (16 lanes each) of one n; k staged in LDS.
// Stream pass keeps only per-j maxima M[15] + D (no U storage -> low VGPR).
// After the monotone-inversion u-threshold is known, qualifying j's re-load
// their float4 (L1/L2-hot) and push candidates to an LDS queue; ONE
// convergent libm eval pass scores them; per-row winner via 64-bit atomicMax
// with (orderable-float-key, ~s) packing (first-index tie-break).
__global__ __launch_bounds__(256) void rel_main(
    const float* __restrict__ radar,   // [W,B,900]
    const float* __restrict__ mde,     // [W,B,900]
    const float* __restrict__ gumbel,  // [N,900,900]
    const float* __restrict__ pWq, const float* __restrict__ pbq,
    const float* __restrict__ pWk, const float* __restrict__ pbk,
    float* __restrict__ out)           // [B,900,W], pre-zeroed
{
    const int tid   = threadIdx.x;
    const int n     = blockIdx.x / BLKS_PER_N;
    const int tbase = (blockIdx.x - n * BLKS_PER_N) * ROWS_PER_BLK;
    const int b     = n >> 3;          // n = b*W + w
    const int w     = n & 7;

    __shared__ float4 ks4[NQ + 1];
    __shared__ float  s_red[8];
    __shared__ float  s_q[ROWS_PER_BLK], s_m[ROWS_PER_BLK], s_D[ROWS_PER_BLK];
    __shared__ unsigned long long s_win[ROWS_PER_BLK];
    __shared__ int    s_cnt;
    __shared__ int    s_qs[CAP];
    __shared__ float  s_qu[CAP];

    if (tid == 0) s_cnt = 0;
    if (tid < ROWS_PER_BLK) s_win[tid] = 0ULL;

    // ---- stage k = fl(mde*Wk + bk) into LDS; exact block min/max ----
    const float wk = pWk[0], bk0 = pbk[0];
    float kmin = FLT_MAX, kmax = -FLT_MAX;
    if (tid < NQ) {
        const float4* __restrict__ m4p = (const float4*)(mde + (size_t)(w * BD + b) * SS);
        float4 mq = m4p[tid];
        float4 k;
        k.x = __fmaf_rn(mq.x, wk, bk0);
        k.y = __fmaf_rn(mq.y, wk, bk0);
        k.z = __fmaf_rn(mq.z, wk, bk0);
        k.w = __fmaf_rn(mq.w, wk, bk0);
        ks4[tid] = k;
        kmin = fminf(fminf(k.x, k.y), fminf(k.z, k.w));
        kmax = fmaxf(fmaxf(k.x, k.y), fmaxf(k.z, k.w));
    }
    #pragma unroll
    for (int off = 1; off < 64; off <<= 1) {
        kmin = fminf(kmin, __shfl_xor(kmin, off, 64));
        kmax = fmaxf(kmax, __shfl_xor(kmax, off, 64));
    }
    if ((tid & 63) == 0) { s_red[tid >> 6] = kmin; s_red[4 + (tid >> 6)] = kmax; }
    __syncthreads();
    kmin = fminf(fminf(s_red[0], s_red[1]), fminf(s_red[2], s_red[3]));
    kmax = fmaxf(fmaxf(s_red[4], s_red[5]), fmaxf(s_red[6], s_red[7]));

    const int gg     = tid >> 4;
    const int lane16 = tid & 15;
    const int t      = tbase + gg;
    const bool active = (t < SS);
    const int tc     = active ? t : 0;       // tail groups do harmless work
    const int row    = n * SS + tc;

    const float r0 = radar[(size_t)(w * BD + b) * SS + tc];
    const float q  = __fmaf_rn(r0, pWq[0], pbq[0]);
    // max_s fl(q*k_s) == fl(q*k_ext) by monotonicity of rounding
    const float m  = __fmul_rn(q, (q >= 0.0f) ? kmax : kmin);

    const float4* __restrict__ g4 = (const float4*)(gumbel + (size_t)row * SS);
    const float*  __restrict__ kf = (const float*)ks4;

    // ---- stream: per-j max M[j] + D = sum __expf(q*k - m) ----
    float M[15];
    float D = 0.0f;
    #pragma unroll
    for (int j = 0; j < 15; j++) {
        const int f = j * 16 + lane16;
        const bool valid = (j < 14) || (lane16 == 0);   // 225 = 14*16 + 1
        const int fc = valid ? f : 0;
        float4 u = g4[fc];
        float4 k = ks4[fc];
        if (!valid) { u.x = u.y = u.z = u.w = -1.0f; }
        M[j] = fmaxf(fmaxf(u.x, u.y), fmaxf(u.z, u.w));
        if (valid) {
            D += __expf(__fmaf_rn(q, k.x, -m)) + __expf(__fmaf_rn(q, k.y, -m))
               + __expf(__fmaf_rn(q, k.z, -m)) + __expf(__fmaf_rn(q, k.w, -m));
        }
    }
    float umax = M[0];
    #pragma unroll
    for (int j = 1; j < 15; j++) umax = fmaxf(umax, M[j]);
    #pragma unroll
    for (int off = 1; off < 16; off <<= 1) {
        umax = fmaxf(umax, __shfl_xor(umax, off, 16));
        D += __shfl_xor(D, off, 16);
    }
    if (active && lane16 == 0) { s_q[gg] = q; s_m[gg] = m; s_D[gg] = D; }

    // ---- u-threshold: winner has nz >= nzmax - margin, margin ~ 1/D ----
    // nz(u) >= T  <=>  u >= exp(-(exp(-T) - 1e-8)) - 1e-8   (monotone).
    // hw __logf/__expf here: filter is inclusive; 1e-5 rel downward fudge
    // absorbs hw-trans error. Precise eval below stays libm.
    float margin = __fmaf_rn(1.002f, 1.0f / D, 1e-6f);
    float w0    = -__logf(umax + 1e-8f);
    float nzmax = -__logf(w0 + 1e-8f);
    float T     = nzmax - margin;
    float wT    = __expf(-T);
    float uthr  = __expf(-(wT - 1e-8f)) - 1e-8f;
    uthr = uthr - fabsf(uthr) * 1e-5f - 1e-9f;   // downward: inclusive filter

    // ---- scan M[]; qualifying j re-loads its float4 and pushes candidates ----
    if (active) {
        #pragma unroll
        for (int j = 0; j < 15; j++) {
            if (M[j] >= uthr) {
                const int f = j * 16 + lane16;
                const bool valid = (j < 14) || (lane16 == 0);
                const int fc = valid ? f : 0;
                float4 u = g4[fc];                 // L1/L2-hot re-read
                if (!valid) { u.x = u.y = u.z = u.w = -1.0f; }
                const int s0 = fc * 4;
                if (u.x >= uthr) { int i2 = atomicAdd(&s_cnt, 1); if (i2 < CAP) { s_qs[i2] = (gg << 10) | s0;       s_qu[i2] = u.x; } }
                if (u.y >= uthr) { int i2 = atomicAdd(&s_cnt, 1); if (i2 < CAP) { s_qs[i2] = (gg << 10) | (s0 + 1); s_qu[i2] = u.y; } }
                if (u.z >= uthr) { int i2 = atomicAdd(&s_cnt, 1); if (i2 < CAP) { s_qs[i2] = (gg << 10) | (s0 + 2); s_qu[i2] = u.z; } }
                if (u.w >= uthr) { int i2 = atomicAdd(&s_cnt, 1); if (i2 < CAP) { s_qs[i2] = (gg << 10) | (s0 + 3); s_qu[i2] = u.w; } }
            }
        }
    }
    __syncthreads();

    // ---- ONE convergent precise eval pass over the block's candidates ----
    const int nc = min(s_cnt, CAP);
    if (tid < nc) {
        int   pk = s_qs[tid];
        int   g2 = pk >> 10, s = pk & 0x3FF;
        float u  = s_qu[tid];
        float q2 = s_q[g2], m2 = s_m[g2], D2 = s_D[g2];
        float l  = __fmul_rn(q2, kf[s]);
        float nz = -logf(-logf(u + 1e-8f) + 1e-8f);
        float v  = expf(l - m2) / D2 + nz;
        unsigned vb = __float_as_uint(v);
        unsigned key32 = (vb & 0x80000000u) ? ~vb : (vb | 0x80000000u);
        unsigned long long key =
            ((unsigned long long)key32 << 32) | (unsigned)(0xFFFFFFFFu - (unsigned)s);
        atomicMax(&s_win[g2], key);
    }
    __syncthreads();

    if (active && lane16 == 0) {
        unsigned long long key = s_win[gg];
        unsigned s = 0xFFFFFFFFu - (unsigned)(key & 0xFFFFFFFFull);
        atomicAdd(&out[((size_t)b * SS + s) * WD + w], r0);
    }
}

// out += valid * (out != 0) * (attn_residual_scale * ln_beta)
__global__ __launch_bounds__(256) void rel_epilogue(
    const float* __restrict__ radar,
    const float* __restrict__ pScale,
    const float* __restrict__ pBeta,
    float* __restrict__ out)
{
    int i = blockIdx.x * 256 + threadIdx.x;
    if (i >= OUT_ELEMS) return;
    int w    = i & 7;
    int rest = i >> 3;
    int s    = rest % SS;
    int b    = rest / SS;
    float o = out[i];
    float r = radar[(size_t)(w * BD + b) * SS + s];
    float add = ((r != 0.0f) && (o != 0.0f)) ? (pScale[0] * pBeta[0]) : 0.0f;
    out[i] = o + add;
}

extern "C" void kernel_launch(void* const* d_in, const int* in_sizes, int n_in,
                              void* d_out, int out_size, void* d_ws, size_t ws_size,
                              hipStream_t stream) {
    const float* radar  = (const float*)d_in[0];
    const float* mde    = (const float*)d_in[1];
    const float* gumbel = (const float*)d_in[2];
    const float* Wq     = (const float*)d_in[3];
    const float* bq     = (const float*)d_in[4];
    const float* Wk     = (const float*)d_in[5];
    const float* bk     = (const float*)d_in[6];
    // d_in[7..11] = Wv, bv, Wo, bo, ln_gamma (dead: LN over dim-1 => attended_out == ln_beta)
    const float* beta   = (const float*)d_in[12];
    const float* scale  = (const float*)d_in[13];
    float* out = (float*)d_out;

    rel_zero<<<(OUT_ELEMS / 4 + 255) / 256, 256, 0, stream>>>((float4*)out);
    rel_main<<<NROWS * BLKS_PER_N, 256, 0, stream>>>(radar, mde, gumbel,
                                                     Wq, bq, Wk, bk, out);
    rel_epilogue<<<(OUT_ELEMS + 255) / 256, 256, 0, stream>>>(radar, scale, beta, out);
}

// Round 7
// 43.964 us; speedup vs baseline: 3.5604x; 1.0133x over previous
//
#include <hip/hip_runtime.h>
#include <cfloat>

#define SS 900      // sequence length (30*30)
#define WD 8
#define BD 8
#define NROWS 64    // B*W
#define OUT_ELEMS (BD * SS * WD)  // 57600
#define NQ 225      // float4s per row (900/4)
#define ROWS_PER_BLK 16
#define BLKS_PER_N 57             // ceil(900/16)
#define CAP 128                   // candidate queue capacity per block

// One block = 16 rows (16 lanes each) of one n; k staged in LDS.
// Stream pass keeps only per-j maxima M[15] + D (no U storage -> low VGPR).
// After the monotone-inversion u-threshold is known, qualifying j's re-load
// their float4 (L1/L2-hot) and push candidates to an LDS queue; ONE
// convergent libm eval pass scores them; per-row winner via 64-bit atomicMax
// with (orderable-float-key, ~s) packing (first-index tie-break).
__global__ __launch_bounds__(256) void rel_main(
    const float* __restrict__ radar,   // [W,B,900]
    const float* __restrict__ mde,     // [W,B,900]
    const float* __restrict__ gumbel,  // [N,900,900]
    const float* __restrict__ pWq, const float* __restrict__ pbq,
    const float* __restrict__ pWk, const float* __restrict__ pbk,
    float* __restrict__ out)           // [B,900,W], pre-zeroed
{
    const int tid   = threadIdx.x;
    const int n     = blockIdx.x / BLKS_PER_N;
    const int tbase = (blockIdx.x - n * BLKS_PER_N) * ROWS_PER_BLK;
    const int b     = n >> 3;          // n = b*W + w
    const int w     = n & 7;

    __shared__ float4 ks4[NQ + 1];
    __shared__ float  s_red[8];
    __shared__ float  s_q[ROWS_PER_BLK], s_m[ROWS_PER_BLK], s_D[ROWS_PER_BLK];
    __shared__ unsigned long long s_win[ROWS_PER_BLK];
    __shared__ int    s_cnt;
    __shared__ int    s_qs[CAP];
    __shared__ float  s_qu[CAP];

    if (tid == 0) s_cnt = 0;
    if (tid < ROWS_PER_BLK) s_win[tid] = 0ULL;

    // ---- stage k = fl(mde*Wk + bk) into LDS; exact block min/max ----
    const float wk = pWk[0], bk0 = pbk[0];
    float kmin = FLT_MAX, kmax = -FLT_MAX;
    if (tid < NQ) {
        const float4* __restrict__ m4p = (const float4*)(mde + (size_t)(w * BD + b) * SS);
        float4 mq = m4p[tid];
        float4 k;
        k.x = __fmaf_rn(mq.x, wk, bk0);
        k.y = __fmaf_rn(mq.y, wk, bk0);
        k.z = __fmaf_rn(mq.z, wk, bk0);
        k.w = __fmaf_rn(mq.w, wk, bk0);
        ks4[tid] = k;
        kmin = fminf(fminf(k.x, k.y), fminf(k.z, k.w));
        kmax = fmaxf(fmaxf(k.x, k.y), fmaxf(k.z, k.w));
    }
    #pragma unroll
    for (int off = 1; off < 64; off <<= 1) {
        kmin = fminf(kmin, __shfl_xor(kmin, off, 64));
        kmax = fmaxf(kmax, __shfl_xor(kmax, off, 64));
    }
    if ((tid & 63) == 0) { s_red[tid >> 6] = kmin; s_red[4 + (tid >> 6)] = kmax; }
    __syncthreads();
    kmin = fminf(fminf(s_red[0], s_red[1]), fminf(s_red[2], s_red[3]));
    kmax = fmaxf(fmaxf(s_red[4], s_red[5]), fmaxf(s_red[6], s_red[7]));

    const int gg     = tid >> 4;
    const int lane16 = tid & 15;
    const int t      = tbase + gg;
    const bool active = (t < SS);
    const int tc     = active ? t : 0;       // tail groups do harmless work
    const int row    = n * SS + tc;

    const float r0 = radar[(size_t)(w * BD + b) * SS + tc];
    const float q  = __fmaf_rn(r0, pWq[0], pbq[0]);
    // max_s fl(q*k_s) == fl(q*k_ext) by monotonicity of rounding
    const float m  = __fmul_rn(q, (q >= 0.0f) ? kmax : kmin);

    const float4* __restrict__ g4 = (const float4*)(gumbel + (size_t)row * SS);
    const float*  __restrict__ kf = (const float*)ks4;

    // ---- stream: per-j max M[j] + D = sum __expf(q*k - m) ----
    float M[15];
    float D = 0.0f;
    #pragma unroll
    for (int j = 0; j < 15; j++) {
        const int f = j * 16 + lane16;
        const bool valid = (j < 14) || (lane16 == 0);   // 225 = 14*16 + 1
        const int fc = valid ? f : 0;
        float4 u = g4[fc];
        float4 k = ks4[fc];
        if (!valid) { u.x = u.y = u.z = u.w = -1.0f; }
        M[j] = fmaxf(fmaxf(u.x, u.y), fmaxf(u.z, u.w));
        if (valid) {
            D += __expf(__fmaf_rn(q, k.x, -m)) + __expf(__fmaf_rn(q, k.y, -m))
               + __expf(__fmaf_rn(q, k.z, -m)) + __expf(__fmaf_rn(q, k.w, -m));
        }
    }
    float umax = M[0];
    #pragma unroll
    for (int j = 1; j < 15; j++) umax = fmaxf(umax, M[j]);
    #pragma unroll
    for (int off = 1; off < 16; off <<= 1) {
        umax = fmaxf(umax, __shfl_xor(umax, off, 16));
        D += __shfl_xor(D, off, 16);
    }
    if (active && lane16 == 0) { s_q[gg] = q; s_m[gg] = m; s_D[gg] = D; }

    // ---- u-threshold: winner has nz >= nzmax - margin, margin ~ 1/D ----
    // nz(u) >= T  <=>  u >= exp(-(exp(-T) - 1e-8)) - 1e-8   (monotone).
    // hw __logf/__expf here: filter is inclusive; 1e-5 rel downward fudge
    // absorbs hw-trans error. Precise eval below stays libm.
    float margin = __fmaf_rn(1.002f, 1.0f / D, 1e-6f);
    float w0    = -__logf(umax + 1e-8f);
    float nzmax = -__logf(w0 + 1e-8f);
    float T     = nzmax - margin;
    float wT    = __expf(-T);
    float uthr  = __expf(-(wT - 1e-8f)) - 1e-8f;
    uthr = uthr - fabsf(uthr) * 1e-5f - 1e-9f;   // downward: inclusive filter

    // ---- scan M[]; qualifying j re-loads its float4 and pushes candidates ----
    if (active) {
        #pragma unroll
        for (int j = 0; j < 15; j++) {
            if (M[j] >= uthr) {
                const int f = j * 16 + lane16;
                const bool valid = (j < 14) || (lane16 == 0);
                const int fc = valid ? f : 0;
                float4 u = g4[fc];                 // L1/L2-hot re-read
                if (!valid) { u.x = u.y = u.z = u.w = -1.0f; }
                const int s0 = fc * 4;
                if (u.x >= uthr) { int i2 = atomicAdd(&s_cnt, 1); if (i2 < CAP) { s_qs[i2] = (gg << 10) | s0;       s_qu[i2] = u.x; } }
                if (u.y >= uthr) { int i2 = atomicAdd(&s_cnt, 1); if (i2 < CAP) { s_qs[i2] = (gg << 10) | (s0 + 1); s_qu[i2] = u.y; } }
                if (u.z >= uthr) { int i2 = atomicAdd(&s_cnt, 1); if (i2 < CAP) { s_qs[i2] = (gg << 10) | (s0 + 2); s_qu[i2] = u.z; } }
                if (u.w >= uthr) { int i2 = atomicAdd(&s_cnt, 1); if (i2 < CAP) { s_qs[i2] = (gg << 10) | (s0 + 3); s_qu[i2] = u.w; } }
            }
        }
    }
    __syncthreads();

    // ---- ONE convergent precise eval pass over the block's candidates ----
    const int nc = min(s_cnt, CAP);
    if (tid < nc) {
        int   pk = s_qs[tid];
        int   g2 = pk >> 10, s = pk & 0x3FF;
        float u  = s_qu[tid];
        float q2 = s_q[g2], m2 = s_m[g2], D2 = s_D[g2];
        float l  = __fmul_rn(q2, kf[s]);
        float nz = -logf(-logf(u + 1e-8f) + 1e-8f);
        float v  = expf(l - m2) / D2 + nz;
        unsigned vb = __float_as_uint(v);
        unsigned key32 = (vb & 0x80000000u) ? ~vb : (vb | 0x80000000u);
        unsigned long long key =
            ((unsigned long long)key32 << 32) | (unsigned)(0xFFFFFFFFu - (unsigned)s);
        atomicMax(&s_win[g2], key);
    }
    __syncthreads();

    if (active && lane16 == 0) {
        unsigned long long key = s_win[gg];
        unsigned s = 0xFFFFFFFFu - (unsigned)(key & 0xFFFFFFFFull);
        atomicAdd(&out[((size_t)b * SS + s) * WD + w], r0);
    }
}

// out += valid * (out != 0) * (attn_residual_scale * ln_beta), float4-wide
__global__ __launch_bounds__(256) void rel_epilogue(
    const float* __restrict__ radar,
    const float* __restrict__ pScale,
    const float* __restrict__ pBeta,
    float4* __restrict__ out4)
{
    int i4 = blockIdx.x * 256 + threadIdx.x;
    if (i4 >= OUT_ELEMS / 4) return;
    const float c = pScale[0] * pBeta[0];
    float4 o = out4[i4];
    int base = i4 * 4;
    #pragma unroll
    for (int e = 0; e < 4; e++) {
        int i = base + e;
        int w    = i & 7;
        int rest = i >> 3;
        int s    = rest % SS;
        int b    = rest / SS;
        float oo = (&o.x)[e];
        float r  = radar[(size_t)(w * BD + b) * SS + s];
        (&o.x)[e] = oo + (((r != 0.0f) && (oo != 0.0f)) ? c : 0.0f);
    }
    out4[i4] = o;
}

extern "C" void kernel_launch(void* const* d_in, const int* in_sizes, int n_in,
                              void* d_out, int out_size, void* d_ws, size_t ws_size,
                              hipStream_t stream) {
    const float* radar  = (const float*)d_in[0];
    const float* mde    = (const float*)d_in[1];
    const float* gumbel = (const float*)d_in[2];
    const float* Wq     = (const float*)d_in[3];
    const float* bq     = (const float*)d_in[4];
    const float* Wk     = (const float*)d_in[5];
    const float* bk     = (const float*)d_in[6];
    // d_in[7..11] = Wv, bv, Wo, bo, ln_gamma (dead: LN over dim-1 => attended_out == ln_beta)
    const float* beta   = (const float*)d_in[12];
    const float* scale  = (const float*)d_in[13];
    float* out = (float*)d_out;

    // zero-init via DMA memset node (graph-capture-safe, cheaper than a kernel)
    hipMemsetAsync(out, 0, (size_t)OUT_ELEMS * sizeof(float), stream);
    rel_main<<<NROWS * BLKS_PER_N, 256, 0, stream>>>(radar, mde, gumbel,
                                                     Wq, bq, Wk, bk, out);
    rel_epilogue<<<(OUT_ELEMS / 4 + 255) / 256, 256, 0, stream>>>(
        radar, scale, beta, (float4*)out);
}

// Round 8
// 41.124 us; speedup vs baseline: 3.8063x; 1.0691x over previous
//
#include <hip/hip_runtime.h>
#include <cfloat>

#define SS 900      // sequence length (30*30)
#define WD 8
#define BD 8
#define NROWS 64    // B*W
#define OUT_ELEMS (BD * SS * WD)  // 57600
#define NQ 225      // float4s per row (900/4)
#define ROWS_PER_BLK 16
#define BLKS_PER_N 57             // ceil(900/16)
#define CAP 128                   // candidate queue capacity per block

// One block = 16 rows (16 lanes each) of one n; k staged in LDS.
// Stream pass keeps only per-j maxima M[15] + D (no U storage -> low VGPR).
// After the monotone-inversion u-threshold is known, qualifying j's re-load
// their float4 (L1/L2-hot) and push candidates to an LDS queue; ONE
// convergent libm eval pass scores them; per-row winner via 64-bit atomicMax
// with (orderable-float-key, ~s) packing (first-index tie-break).
// Winner INDEX goes to idxbuf (no global scatter; out handled by rel_final).
__global__ __launch_bounds__(256) void rel_main(
    const float* __restrict__ radar,   // [W,B,900]
    const float* __restrict__ mde,     // [W,B,900]
    const float* __restrict__ gumbel,  // [N,900,900]
    const float* __restrict__ pWq, const float* __restrict__ pbq,
    const float* __restrict__ pWk, const float* __restrict__ pbk,
    int* __restrict__ idxbuf)          // [64][900]
{
    const int tid   = threadIdx.x;
    const int n     = blockIdx.x / BLKS_PER_N;
    const int tbase = (blockIdx.x - n * BLKS_PER_N) * ROWS_PER_BLK;
    const int b     = n >> 3;          // n = b*W + w
    const int w     = n & 7;

    __shared__ float4 ks4[NQ + 1];
    __shared__ float  s_red[8];
    __shared__ float  s_q[ROWS_PER_BLK], s_m[ROWS_PER_BLK], s_D[ROWS_PER_BLK];
    __shared__ unsigned long long s_win[ROWS_PER_BLK];
    __shared__ int    s_cnt;
    __shared__ int    s_qs[CAP];
    __shared__ float  s_qu[CAP];

    if (tid == 0) s_cnt = 0;
    if (tid < ROWS_PER_BLK) s_win[tid] = 0ULL;

    // ---- stage k = fl(mde*Wk + bk) into LDS; exact block min/max ----
    const float wk = pWk[0], bk0 = pbk[0];
    float kmin = FLT_MAX, kmax = -FLT_MAX;
    if (tid < NQ) {
        const float4* __restrict__ m4p = (const float4*)(mde + (size_t)(w * BD + b) * SS);
        float4 mq = m4p[tid];
        float4 k;
        k.x = __fmaf_rn(mq.x, wk, bk0);
        k.y = __fmaf_rn(mq.y, wk, bk0);
        k.z = __fmaf_rn(mq.z, wk, bk0);
        k.w = __fmaf_rn(mq.w, wk, bk0);
        ks4[tid] = k;
        kmin = fminf(fminf(k.x, k.y), fminf(k.z, k.w));
        kmax = fmaxf(fmaxf(k.x, k.y), fmaxf(k.z, k.w));
    }
    #pragma unroll
    for (int off = 1; off < 64; off <<= 1) {
        kmin = fminf(kmin, __shfl_xor(kmin, off, 64));
        kmax = fmaxf(kmax, __shfl_xor(kmax, off, 64));
    }
    if ((tid & 63) == 0) { s_red[tid >> 6] = kmin; s_red[4 + (tid >> 6)] = kmax; }
    __syncthreads();
    kmin = fminf(fminf(s_red[0], s_red[1]), fminf(s_red[2], s_red[3]));
    kmax = fmaxf(fmaxf(s_red[4], s_red[5]), fmaxf(s_red[6], s_red[7]));

    const int gg     = tid >> 4;
    const int lane16 = tid & 15;
    const int t      = tbase + gg;
    const bool active = (t < SS);
    const int tc     = active ? t : 0;       // tail groups do harmless work
    const int row    = n * SS + tc;

    const float r0 = radar[(size_t)(w * BD + b) * SS + tc];
    const float q  = __fmaf_rn(r0, pWq[0], pbq[0]);
    // max_s fl(q*k_s) == fl(q*k_ext) by monotonicity of rounding
    const float m  = __fmul_rn(q, (q >= 0.0f) ? kmax : kmin);

    const float4* __restrict__ g4 = (const float4*)(gumbel + (size_t)row * SS);
    const float*  __restrict__ kf = (const float*)ks4;

    // ---- stream: per-j max M[j] + D = sum __expf(q*k - m) ----
    float M[15];
    float D = 0.0f;
    #pragma unroll
    for (int j = 0; j < 15; j++) {
        const int f = j * 16 + lane16;
        const bool valid = (j < 14) || (lane16 == 0);   // 225 = 14*16 + 1
        const int fc = valid ? f : 0;
        float4 u = g4[fc];
        float4 k = ks4[fc];
        if (!valid) { u.x = u.y = u.z = u.w = -1.0f; }
        M[j] = fmaxf(fmaxf(u.x, u.y), fmaxf(u.z, u.w));
        if (valid) {
            D += __expf(__fmaf_rn(q, k.x, -m)) + __expf(__fmaf_rn(q, k.y, -m))
               + __expf(__fmaf_rn(q, k.z, -m)) + __expf(__fmaf_rn(q, k.w, -m));
        }
    }
    float umax = M[0];
    #pragma unroll
    for (int j = 1; j < 15; j++) umax = fmaxf(umax, M[j]);
    #pragma unroll
    for (int off = 1; off < 16; off <<= 1) {
        umax = fmaxf(umax, __shfl_xor(umax, off, 16));
        D += __shfl_xor(D, off, 16);
    }
    if (active && lane16 == 0) { s_q[gg] = q; s_m[gg] = m; s_D[gg] = D; }

    // ---- u-threshold: winner has nz >= nzmax - margin, margin ~ 1/D ----
    // nz(u) >= T  <=>  u >= exp(-(exp(-T) - 1e-8)) - 1e-8   (monotone).
    // hw __logf/__expf here: filter is inclusive; 1e-5 rel downward fudge
    // absorbs hw-trans error. Precise eval below stays libm.
    float margin = __fmaf_rn(1.002f, 1.0f / D, 1e-6f);
    float w0    = -__logf(umax + 1e-8f);
    float nzmax = -__logf(w0 + 1e-8f);
    float T     = nzmax - margin;
    float wT    = __expf(-T);
    float uthr  = __expf(-(wT - 1e-8f)) - 1e-8f;
    uthr = uthr - fabsf(uthr) * 1e-5f - 1e-9f;   // downward: inclusive filter

    // ---- scan M[]; qualifying j re-loads its float4 and pushes candidates ----
    if (active) {
        #pragma unroll
        for (int j = 0; j < 15; j++) {
            if (M[j] >= uthr) {
                const int f = j * 16 + lane16;
                const bool valid = (j < 14) || (lane16 == 0);
                const int fc = valid ? f : 0;
                float4 u = g4[fc];                 // L1/L2-hot re-read
                if (!valid) { u.x = u.y = u.z = u.w = -1.0f; }
                const int s0 = fc * 4;
                if (u.x >= uthr) { int i2 = atomicAdd(&s_cnt, 1); if (i2 < CAP) { s_qs[i2] = (gg << 10) | s0;       s_qu[i2] = u.x; } }
                if (u.y >= uthr) { int i2 = atomicAdd(&s_cnt, 1); if (i2 < CAP) { s_qs[i2] = (gg << 10) | (s0 + 1); s_qu[i2] = u.y; } }
                if (u.z >= uthr) { int i2 = atomicAdd(&s_cnt, 1); if (i2 < CAP) { s_qs[i2] = (gg << 10) | (s0 + 2); s_qu[i2] = u.z; } }
                if (u.w >= uthr) { int i2 = atomicAdd(&s_cnt, 1); if (i2 < CAP) { s_qs[i2] = (gg << 10) | (s0 + 3); s_qu[i2] = u.w; } }
            }
        }
    }
    __syncthreads();

    // ---- ONE convergent precise eval pass over the block's candidates ----
    const int nc = min(s_cnt, CAP);
    if (tid < nc) {
        int   pk = s_qs[tid];
        int   g2 = pk >> 10, s = pk & 0x3FF;
        float u  = s_qu[tid];
        float q2 = s_q[g2], m2 = s_m[g2], D2 = s_D[g2];
        float l  = __fmul_rn(q2, kf[s]);
        float nz = -logf(-logf(u + 1e-8f) + 1e-8f);
        float v  = expf(l - m2) / D2 + nz;
        unsigned vb = __float_as_uint(v);
        unsigned key32 = (vb & 0x80000000u) ? ~vb : (vb | 0x80000000u);
        unsigned long long key =
            ((unsigned long long)key32 << 32) | (unsigned)(0xFFFFFFFFu - (unsigned)s);
        atomicMax(&s_win[g2], key);
    }
    __syncthreads();

    if (active && lane16 == 0) {
        unsigned long long key = s_win[gg];
        unsigned s = 0xFFFFFFFFu - (unsigned)(key & 0xFFFFFFFFull);
        idxbuf[n * SS + t] = (int)s;
    }
}

// One block per n: gather radar[t] into acc[idx[t]] via LDS atomics, then
// write EVERY out element with the epilogue fused (no pre-zero, no RMW):
// out[b,s,w] = acc[s] + (radar[s]!=0 && acc[s]!=0) * scale*beta
__global__ __launch_bounds__(1024) void rel_final(
    const float* __restrict__ radar,   // [W,B,900]
    const int* __restrict__ idxbuf,    // [64][900]
    const float* __restrict__ pScale,
    const float* __restrict__ pBeta,
    float* __restrict__ out)           // [B,900,W]
{
    const int n = blockIdx.x;
    const int b = n >> 3, w = n & 7;
    const int tid = threadIdx.x;

    __shared__ float acc[SS];
    __shared__ float rad[SS];

    if (tid < SS) {
        acc[tid] = 0.0f;
        rad[tid] = radar[(size_t)(w * BD + b) * SS + tid];
    }
    __syncthreads();
    if (tid < SS) {
        int s = idxbuf[n * SS + tid];
        atomicAdd(&acc[s], rad[tid]);
    }
    __syncthreads();
    if (tid < SS) {
        const float c = pScale[0] * pBeta[0];
        float o = acc[tid];
        float r = rad[tid];
        out[((size_t)b * SS + tid) * WD + w] =
            o + (((r != 0.0f) && (o != 0.0f)) ? c : 0.0f);
    }
}

extern "C" void kernel_launch(void* const* d_in, const int* in_sizes, int n_in,
                              void* d_out, int out_size, void* d_ws, size_t ws_size,
                              hipStream_t stream) {
    const float* radar  = (const float*)d_in[0];
    const float* mde    = (const float*)d_in[1];
    const float* gumbel = (const float*)d_in[2];
    const float* Wq     = (const float*)d_in[3];
    const float* bq     = (const float*)d_in[4];
    const float* Wk     = (const float*)d_in[5];
    const float* bk     = (const float*)d_in[6];
    // d_in[7..11] = Wv, bv, Wo, bo, ln_gamma (dead: LN over dim-1 => attended_out == ln_beta)
    const float* beta   = (const float*)d_in[12];
    const float* scale  = (const float*)d_in[13];
    float* out = (float*)d_out;

    int* idxbuf = (int*)d_ws;          // [64][900], fully overwritten each call

    rel_main<<<NROWS * BLKS_PER_N, 256, 0, stream>>>(radar, mde, gumbel,
                                                     Wq, bq, Wk, bk, idxbuf);
    rel_final<<<NROWS, 1024, 0, stream>>>(radar, idxbuf, scale, beta, out);
}